// Round 10
// baseline (250.085 us; speedup 1.0000x reference)
//
#include <hip/hip_runtime.h>
#include <hip/hip_bf16.h>

#define M_ROWS 17664   // B*T = 64*276
#define K_CODES 8192
#define D_DIM 256
#define N_ELEM 4521984 // M_ROWS * 256

typedef unsigned short ushort_t;
typedef __attribute__((ext_vector_type(8))) short short8v;  // 8 bf16 (4 VGPRs)
typedef __attribute__((ext_vector_type(4))) float f32x4;

__device__ __forceinline__ unsigned long long umin64(unsigned long long a, unsigned long long b) { return a < b ? a : b; }

__device__ __forceinline__ unsigned long long shflxor64(unsigned long long v, int m) {
    unsigned lo = (unsigned)v, hi = (unsigned)(v >> 32);
    lo = __shfl_xor(lo, m);
    hi = __shfl_xor(hi, m);
    return ((unsigned long long)hi << 32) | lo;
}

__device__ __forceinline__ void gload16(const void* g, void* l) {
    __builtin_amdgcn_global_load_lds((const __attribute__((address_space(1))) void*)g,
                                     (__attribute__((address_space(3))) void*)l, 16, 0, 0);
}

// ---------------------------------------------------------------------------
// Fused prep (ONE launch for both inputs): coalesced read of 32 rows -> bf16
// copy + EXACT numpy pairwise sum-of-squares (verified chain). LDS stride 257.
// Block 0 also inits loss_acc and the phase2 completion ticket.
// ---------------------------------------------------------------------------
__global__ __launch_bounds__(256) void prep_kernel(
    const float* __restrict__ Z, const float* __restrict__ CB,
    ushort_t* __restrict__ Zb, ushort_t* __restrict__ Cb,
    float* __restrict__ asum, float* __restrict__ bsum,
    float* __restrict__ loss_acc, unsigned* __restrict__ ticket) {
    __shared__ float S[32][257];
    const int t = threadIdx.x;
    const int bid = blockIdx.x;
    const float* X; ushort_t* Xb; float* sums; int r0;
    if (bid < M_ROWS / 32) { X = Z; Xb = Zb; sums = asum; r0 = bid * 32; }
    else { X = CB; Xb = Cb; sums = bsum; r0 = (bid - M_ROWS / 32) * 32; }
    if (bid == 0 && t == 0) { loss_acc[0] = 0.0f; ticket[0] = 0u; }
#pragma unroll
    for (int it = 0; it < 8; ++it) {
        int idx4 = t + it * 256;
        int row = idx4 >> 6;
        int c4 = (idx4 & 63) * 4;
        const float4 v = *(const float4*)(X + (size_t)(r0 + row) * D_DIM + c4);
        float vv[4] = {v.x, v.y, v.z, v.w};
        ushort_t h[4];
#pragma unroll
        for (int j = 0; j < 4; ++j) {
            __hip_bfloat16 b = __float2bfloat16(vv[j]);
            h[j] = *reinterpret_cast<ushort_t*>(&b);
        }
        *(ushort4*)(Xb + (size_t)(r0 + row) * D_DIM + c4) =
            make_ushort4(h[0], h[1], h[2], h[3]);
        S[row][c4 + 0] = v.x; S[row][c4 + 1] = v.y;
        S[row][c4 + 2] = v.z; S[row][c4 + 3] = v.w;
    }
    __syncthreads();
    if (t < 32) {
        float half_sum[2];
#pragma unroll
        for (int h = 0; h < 2; ++h) {
            const float* q = &S[t][h * 128];
            float acc[8];
#pragma unroll
            for (int j = 0; j < 8; ++j) acc[j] = __fmul_rn(q[j], q[j]);
            for (int i = 8; i < 128; i += 8) {
#pragma unroll
                for (int j = 0; j < 8; ++j)
                    acc[j] = __fadd_rn(acc[j], __fmul_rn(q[i + j], q[i + j]));
            }
            float s01 = __fadd_rn(acc[0], acc[1]);
            float s23 = __fadd_rn(acc[2], acc[3]);
            float s45 = __fadd_rn(acc[4], acc[5]);
            float s67 = __fadd_rn(acc[6], acc[7]);
            half_sum[h] = __fadd_rn(__fadd_rn(s01, s23), __fadd_rn(s45, s67));
        }
        sums[r0 + t] = __fadd_rn(half_sum[0], half_sum[1]);
    }
}

// ---------------------------------------------------------------------------
// Phase 1: bf16 MFMA GEMM (Keff=256), 128x128 tile, 4 waves, BK=64,
// SINGLE-buffer (32KB LDS -> 4 blocks/CU) with mid-chunk reissue:
// per chunk: vmcnt(0)+barrier -> ds_read ks0 -> MFMA ks0 -> ds_read ks1 ->
// lgkmcnt(0)+sched_barrier+barrier (all buffer reads done) -> reissue buffer
// for chunk c+1 -> MFMA ks1 (covers load latency; 4 blocks/CU cross-hide).
// BK=64 geometry = R5/R6's measured-ZERO-conflict swizzle (128-B rows,
// slot^(row&7)) on BOTH the pre-swizzled global source (linear gload_lds
// dest, rule #21) and the ds_read slot. MFMA K-order ascending -> acc
// bit-identical to R7/R9. Epilogue unchanged:
// blockcand[M][64 bn][2] u32 (d_rel embed, 13-bit col in cleared mantissa).
// ---------------------------------------------------------------------------
__global__ __launch_bounds__(256, 4) void phase1_kernel(
    const ushort_t* __restrict__ Zb,   // [M][256] bf16 bits
    const ushort_t* __restrict__ Cb,   // [K][256] bf16 bits
    const float* __restrict__ bsum,
    unsigned* __restrict__ blockcand) {
    __shared__ ushort_t As[8192];      // z : 128 rows x 64 K-shorts = 16KB
    __shared__ ushort_t Bs[8192];      // cb: 16KB

    const int t = threadIdx.x;
    const int wid = t >> 6, lane = t & 63;
    const int wm = wid >> 1, wn = wid & 1;

    // bijective XCD-grouped mapping: 8832 = 8 xcd * 8 bnsub * 138 bm
    const int bid = blockIdx.x;
    const int bn = ((bid & 7) << 3) + ((bid >> 3) & 7);
    const int bm = bid >> 6;
    const int m0 = bm * 128, n0 = bn * 128;

    f32x4 acc[4][4];
#pragma unroll
    for (int i = 0; i < 4; ++i)
#pragma unroll
        for (int jj = 0; jj < 4; ++jj) acc[i][jj] = (f32x4){0.f, 0.f, 0.f, 0.f};

    // staging geometry (pre-swizzled source slot; linear gload_lds dest).
    // thread t stages rows (t>>3)+i*32, LDS slot t&7; source slot XOR row&7.
    const int srow8 = t >> 3;                 // 0..31
    const int sslot = t & 7;
    const int srcq = (sslot ^ (srow8 & 7)) * 8;          // shorts
    const ushort_t* zsrc = Zb + (size_t)(m0 + srow8) * 256 + srcq;
    const ushort_t* csrc = Cb + (size_t)(n0 + srow8) * 256 + srcq;
    const int dst0 = srow8 * 64 + sslot * 8;             // shorts; + i*2048

    // fragment read geometry (R5/R6 proven: phys = (ks*4+q) ^ (fr&7))
    const int fr = lane & 15, q = lane >> 4;
    const int ph0 = (q ^ (fr & 7)) * 8;                  // ks=0, shorts
    const int ph1 = ((4 + q) ^ (fr & 7)) * 8;            // ks=1, shorts

    // ---- prologue: stage chunk 0 ----
#pragma unroll
    for (int i = 0; i < 4; ++i) {
        gload16(zsrc + (size_t)i * 8192, &As[dst0 + i * 2048]);
        gload16(csrc + (size_t)i * 8192, &Bs[dst0 + i * 2048]);
    }

    // ---- main loop: 4 chunks of K=64 ----
#pragma unroll
    for (int c = 0; c < 4; ++c) {
        asm volatile("s_waitcnt vmcnt(0)" ::: "memory");
        __builtin_amdgcn_s_barrier();            // chunk c staged for all waves
        asm volatile("" ::: "memory");

        short8v a0[4], b0[4];
#pragma unroll
        for (int mi = 0; mi < 4; ++mi)
            a0[mi] = *(const short8v*)(&Bs[(wn * 64 + mi * 16 + fr) * 64 + ph0]);
#pragma unroll
        for (int nj = 0; nj < 4; ++nj)
            b0[nj] = *(const short8v*)(&As[(wm * 64 + nj * 16 + fr) * 64 + ph0]);
        __builtin_amdgcn_s_setprio(1);
#pragma unroll
        for (int mi = 0; mi < 4; ++mi)
#pragma unroll
            for (int nj = 0; nj < 4; ++nj)
                acc[mi][nj] = __builtin_amdgcn_mfma_f32_16x16x32_bf16(
                    a0[mi], b0[nj], acc[mi][nj], 0, 0, 0);
        __builtin_amdgcn_s_setprio(0);

        short8v a1[4], b1[4];
#pragma unroll
        for (int mi = 0; mi < 4; ++mi)
            a1[mi] = *(const short8v*)(&Bs[(wn * 64 + mi * 16 + fr) * 64 + ph1]);
#pragma unroll
        for (int nj = 0; nj < 4; ++nj)
            b1[nj] = *(const short8v*)(&As[(wm * 64 + nj * 16 + fr) * 64 + ph1]);
        asm volatile("s_waitcnt lgkmcnt(0)" ::: "memory");
        __builtin_amdgcn_sched_barrier(0);
        __builtin_amdgcn_s_barrier();            // all waves done reading buffer
        asm volatile("" ::: "memory");

        if (c < 3) {                             // reissue buffer for chunk c+1
            const int kc = (c + 1) * 64;         // shorts
#pragma unroll
            for (int i = 0; i < 4; ++i) {
                gload16(zsrc + (size_t)i * 8192 + kc, &As[dst0 + i * 2048]);
                gload16(csrc + (size_t)i * 8192 + kc, &Bs[dst0 + i * 2048]);
            }
        }

        __builtin_amdgcn_s_setprio(1);
#pragma unroll
        for (int mi = 0; mi < 4; ++mi)
#pragma unroll
            for (int nj = 0; nj < 4; ++nj)
                acc[mi][nj] = __builtin_amdgcn_mfma_f32_16x16x32_bf16(
                    a1[mi], b1[nj], acc[mi][nj], 0, 0, 0);
        __builtin_amdgcn_s_setprio(0);
    }

    // ---- epilogue: per z-row top-2 over this wave's 64 cb-cols ----
    unsigned* cand = (unsigned*)&As[0];          // [128][9 stride] u32
    const int colb = n0 + wn * 64 + q * 4;
    float bc16[16];
#pragma unroll
    for (int mi = 0; mi < 4; ++mi)
#pragma unroll
        for (int r = 0; r < 4; ++r)
            bc16[mi * 4 + r] = bsum[colb + mi * 16 + r];

    const float INF = __uint_as_float(0x7f800000u);
#pragma unroll
    for (int nj = 0; nj < 4; ++nj) {
        float m1 = INF, m2 = INF;
#pragma unroll
        for (int mi = 0; mi < 4; ++mi)
#pragma unroll
            for (int r = 0; r < 4; ++r) {
                float dm = __builtin_fmaf(-2.0f, acc[mi][nj][r], bc16[mi * 4 + r]);
                unsigned e = (__float_as_uint(dm) & 0xFFFFE000u) |
                             (unsigned)(colb + mi * 16 + r);
                float fe = __uint_as_float(e);
                m2 = __builtin_amdgcn_fmed3f(m1, m2, fe);
                m1 = fminf(m1, fe);
            }
#pragma unroll
        for (int s = 16; s <= 32; s <<= 1) {
            float o1 = __shfl_xor(m1, s);
            float o2 = __shfl_xor(m2, s);
            float nm2 = fminf(fmaxf(m1, o1), fminf(m2, o2));
            m1 = fminf(m1, o1);
            m2 = nm2;
        }
        if (q == 0) {
            int zr = wm * 64 + nj * 16 + fr;     // 0..127 local row
            cand[zr * 9 + wn * 2 + 0] = __float_as_uint(m1);
            cand[zr * 9 + wn * 2 + 1] = __float_as_uint(m2);
        }
    }
    __syncthreads();
    if (t < 128) {
        float b1 = INF, b2 = INF;
#pragma unroll
        for (int j = 0; j < 4; ++j) {
            float f = __uint_as_float(cand[t * 9 + j]);
            b2 = __builtin_amdgcn_fmed3f(b1, b2, f);
            b1 = fminf(b1, f);
        }
        *(uint2*)(blockcand + (size_t)(m0 + t) * 128 + bn * 2) =
            make_uint2(__float_as_uint(b1), __float_as_uint(b2));
    }
}

// ---------------------------------------------------------------------------
// Phase 2 + finalize + losses: per row (one wave), scan 128 u32 candidates,
// threshold at dmin_rel + 5e-4, exact fp32 np-structured distance per
// survivor, index tiebreak, z_q_st / min_idx / loss as the verified path.
// Last block (ticket) writes the loss outputs -- no separate launch.
// ---------------------------------------------------------------------------
__global__ __launch_bounds__(256) void phase2_kernel(
    const float* __restrict__ Z, const float* __restrict__ CB,
    const float* __restrict__ asum, const float* __restrict__ bsum,
    const unsigned* __restrict__ blockcand,
    float* __restrict__ out, float* __restrict__ loss_acc,
    unsigned* __restrict__ ticket) {
    float* out_zq = out + 2;
    float* out_idx = out + 2 + (size_t)N_ELEM;
    const int lane = threadIdx.x & 63;
    const int w = threadIdx.x >> 6;
    const int row = blockIdx.x * 4 + w;
    float lsum = 0.0f;

    if (row < M_ROWS) {
        const uint2 E = *(const uint2*)(blockcand + (size_t)row * 128 + lane * 2);
        float f0 = __uint_as_float(E.x), f1 = __uint_as_float(E.y);
        float mn = fminf(f0, f1);
#pragma unroll
        for (int s = 1; s < 64; s <<= 1) mn = fminf(mn, __shfl_xor(mn, s));
        const float thr = mn + 5.0e-4f;
        unsigned long long k0m = __ballot(f0 <= thr);
        unsigned long long k1m = __ballot(f1 <= thr);

        const float4 zv = *(const float4*)(Z + (size_t)row * D_DIM + lane * 4);
        float ar = asum[row];
        unsigned long long best = 0xFFFFFFFFFFFFFFFFull;

        while (k0m | k1m) {
            unsigned e;
            if (k0m) { int b = __ffsll(k0m) - 1; k0m &= k0m - 1; e = __shfl(E.x, b); }
            else     { int b = __ffsll(k1m) - 1; k1m &= k1m - 1; e = __shfl(E.y, b); }
            unsigned col = e & 8191u;
            const float4 cv = *(const float4*)(CB + (size_t)col * D_DIM + lane * 4);
            float s = __fmul_rn(zv.x, cv.x);
            s = __builtin_fmaf(zv.y, cv.y, s);
            s = __builtin_fmaf(zv.z, cv.z, s);
            s = __builtin_fmaf(zv.w, cv.w, s);
#pragma unroll
            for (int m = 1; m < 64; m <<= 1) s += __shfl_xor(s, m);
            float d = __fsub_rn(__fadd_rn(ar, bsum[col]), __fmul_rn(2.0f, s));
            unsigned long long p = ((unsigned long long)__float_as_uint(d) << 32) | col;
            best = umin64(best, p);
        }

        unsigned wincol = (unsigned)best;
        if (lane == 0) out_idx[row] = (float)wincol;
        const float4 cv = *(const float4*)(CB + (size_t)wincol * D_DIM + lane * 4);
        float d0 = __fsub_rn(cv.x, zv.x);
        float d1 = __fsub_rn(cv.y, zv.y);
        float d2 = __fsub_rn(cv.z, zv.z);
        float d3 = __fsub_rn(cv.w, zv.w);
        float2 o0 = make_float2(__fadd_rn(zv.x, d0), __fadd_rn(zv.y, d1));
        float2 o1 = make_float2(__fadd_rn(zv.z, d2), __fadd_rn(zv.w, d3));
        *(float2*)(out_zq + (size_t)row * D_DIM + lane * 4) = o0;
        *(float2*)(out_zq + (size_t)row * D_DIM + lane * 4 + 2) = o1;
        lsum = d0 * d0 + d1 * d1 + d2 * d2 + d3 * d3;
    }
#pragma unroll
    for (int m = 1; m < 64; m <<= 1) lsum += __shfl_xor(lsum, m);
    __shared__ float red[4];
    if (lane == 0) red[w] = lsum;
    __syncthreads();
    if (threadIdx.x == 0) {
        float s = ((red[0] + red[1]) + (red[2] + red[3]));
        atomicAdd(loss_acc, s);
        __threadfence();
        unsigned my = atomicAdd(ticket, 1u);
        if (my == gridDim.x - 1) {
            __threadfence();
            float l = __fdiv_rn(loss_acc[0], (float)N_ELEM);
            out[0] = l;
            out[1] = l;
        }
    }
}

// ======================= fallback path (fp32 VALU, verified) ================
#define BM 128
#define BN 128
#define BK 32
#define LDT 132

__global__ void rowsq_kernel(const float* __restrict__ X,
                             float* __restrict__ out, int rows) {
    int r = blockIdx.x * blockDim.x + threadIdx.x;
    if (r >= rows) return;
    const float* p = X + (size_t)r * D_DIM;
    float half_sum[2];
#pragma unroll
    for (int h = 0; h < 2; ++h) {
        const float* q = p + h * 128;
        float acc[8];
#pragma unroll
        for (int j = 0; j < 8; ++j) acc[j] = __fmul_rn(q[j], q[j]);
        for (int i = 8; i < 128; i += 8) {
#pragma unroll
            for (int j = 0; j < 8; ++j)
                acc[j] = __fadd_rn(acc[j], __fmul_rn(q[i + j], q[i + j]));
        }
        float s01 = __fadd_rn(acc[0], acc[1]);
        float s23 = __fadd_rn(acc[2], acc[3]);
        float s45 = __fadd_rn(acc[4], acc[5]);
        float s67 = __fadd_rn(acc[6], acc[7]);
        half_sum[h] = __fadd_rn(__fadd_rn(s01, s23), __fadd_rn(s45, s67));
    }
    out[r] = __fadd_rn(half_sum[0], half_sum[1]);
}

__global__ void init_kernel(unsigned long long* __restrict__ packed,
                            float* __restrict__ loss_acc) {
    int i = blockIdx.x * blockDim.x + threadIdx.x;
    if (i < M_ROWS) packed[i] = 0xFFFFFFFFFFFFFFFFull;
    if (i == 0) loss_acc[0] = 0.0f;
}

__global__ __launch_bounds__(256) void gemm_argmin_kernel(
    const float* __restrict__ Z, const float* __restrict__ CB,
    const float* __restrict__ asum, const float* __restrict__ bsum,
    unsigned long long* __restrict__ packed) {
    __shared__ float As[BK][LDT];
    __shared__ float Bs[BK][LDT];
    const int bid = blockIdx.x;
    const int bm = bid >> 6, bn = bid & 63;
    const int m0 = bm * BM, n0 = bn * BN;
    const int t = threadIdx.x;
    const int ty = t >> 4, tx = t & 15;
    float acc[8][8];
#pragma unroll
    for (int i = 0; i < 8; ++i)
#pragma unroll
        for (int j = 0; j < 8; ++j) acc[i][j] = 0.0f;
    for (int k0 = 0; k0 < D_DIM; k0 += BK) {
#pragma unroll
        for (int i = 0; i < 4; ++i) {
            int idx = t + i * 256;
            int row = idx >> 3, kq = idx & 7;
            const float4 av = *(const float4*)(Z + (size_t)(m0 + row) * D_DIM + k0 + kq * 4);
            As[kq * 4 + 0][row] = av.x; As[kq * 4 + 1][row] = av.y;
            As[kq * 4 + 2][row] = av.z; As[kq * 4 + 3][row] = av.w;
            const float4 bv = *(const float4*)(CB + (size_t)(n0 + row) * D_DIM + k0 + kq * 4);
            Bs[kq * 4 + 0][row] = bv.x; Bs[kq * 4 + 1][row] = bv.y;
            Bs[kq * 4 + 2][row] = bv.z; Bs[kq * 4 + 3][row] = bv.w;
        }
        __syncthreads();
#pragma unroll
        for (int k = 0; k < BK; ++k) {
            float af[8], bf[8];
            *(float4*)(af)     = *(const float4*)(&As[k][ty * 4]);
            *(float4*)(af + 4) = *(const float4*)(&As[k][64 + ty * 4]);
            *(float4*)(bf)     = *(const float4*)(&Bs[k][tx * 4]);
            *(float4*)(bf + 4) = *(const float4*)(&Bs[k][64 + tx * 4]);
#pragma unroll
            for (int i = 0; i < 8; ++i)
#pragma unroll
                for (int j = 0; j < 8; ++j)
                    acc[i][j] = __builtin_fmaf(af[i], bf[j], acc[i][j]);
        }
        __syncthreads();
    }
    float ar[8], bc[8];
    int rowIdx[8], colIdx[8];
#pragma unroll
    for (int i = 0; i < 8; ++i) {
        rowIdx[i] = (i < 4) ? (4 * ty + i) : (64 + 4 * ty + (i - 4));
        ar[i] = asum[m0 + rowIdx[i]];
    }
#pragma unroll
    for (int j = 0; j < 8; ++j) {
        colIdx[j] = (j < 4) ? (4 * tx + j) : (64 + 4 * tx + (j - 4));
        bc[j] = bsum[n0 + colIdx[j]];
    }
#pragma unroll
    for (int i = 0; i < 8; ++i) {
        unsigned long long best = 0xFFFFFFFFFFFFFFFFull;
#pragma unroll
        for (int j = 0; j < 8; ++j) {
            float ts = __fadd_rn(ar[i], bc[j]);
            float d = __fsub_rn(ts, __fmul_rn(2.0f, acc[i][j]));
            unsigned long long p = ((unsigned long long)__float_as_uint(d) << 32) |
                                   (unsigned)(n0 + colIdx[j]);
            best = (p < best) ? p : best;
        }
#pragma unroll
        for (int m = 1; m <= 8; m <<= 1) {
            unsigned long long o = shflxor64(best, m);
            best = (o < best) ? o : best;
        }
        if (tx == 0) atomicMin(&packed[m0 + rowIdx[i]], best);
    }
}

__global__ __launch_bounds__(256) void finalize_kernel(
    const float* __restrict__ Z, const float* __restrict__ CB,
    const unsigned long long* __restrict__ packed,
    float* __restrict__ out, float* __restrict__ loss_acc) {
    float* out_zq = out + 2;
    float* out_idx = out + 2 + (size_t)N_ELEM;
    const int lane = threadIdx.x & 63;
    const int wid = (blockIdx.x * blockDim.x + threadIdx.x) >> 6;
    const int nw = (gridDim.x * blockDim.x) >> 6;
    float lsum = 0.0f;
    for (int row = wid; row < M_ROWS; row += nw) {
        unsigned long long pk = packed[row];
        unsigned idx = (unsigned)(pk & 0xFFFFFFFFull);
        if (lane == 0) out_idx[row] = (float)idx;
        const float4 zv = *(const float4*)(Z + (size_t)row * D_DIM + lane * 4);
        const float4 cv = *(const float4*)(CB + (size_t)idx * D_DIM + lane * 4);
        float d0 = __fsub_rn(cv.x, zv.x);
        float d1 = __fsub_rn(cv.y, zv.y);
        float d2 = __fsub_rn(cv.z, zv.z);
        float d3 = __fsub_rn(cv.w, zv.w);
        float2 o0 = make_float2(__fadd_rn(zv.x, d0), __fadd_rn(zv.y, d1));
        float2 o1 = make_float2(__fadd_rn(zv.z, d2), __fadd_rn(zv.w, d3));
        *(float2*)(out_zq + (size_t)row * D_DIM + lane * 4) = o0;
        *(float2*)(out_zq + (size_t)row * D_DIM + lane * 4 + 2) = o1;
        lsum += d0 * d0 + d1 * d1 + d2 * d2 + d3 * d3;
    }
#pragma unroll
    for (int m = 1; m < 64; m <<= 1) lsum += __shfl_xor(lsum, m);
    __shared__ float red[4];
    if (lane == 0) red[threadIdx.x >> 6] = lsum;
    __syncthreads();
    if (threadIdx.x == 0) {
        float s = ((red[0] + red[1]) + (red[2] + red[3]));
        atomicAdd(loss_acc, s);
    }
}

__global__ void write_losses(const float* __restrict__ loss_acc,
                             float* __restrict__ out) {
    float l = __fdiv_rn(loss_acc[0], (float)N_ELEM);
    out[0] = l;
    out[1] = l;
}

// ===========================================================================
extern "C" void kernel_launch(void* const* d_in, const int* in_sizes, int n_in,
                              void* d_out, int out_size, void* d_ws, size_t ws_size,
                              hipStream_t stream) {
    const float* Z = (const float*)d_in[0];    // [17664, 256]
    const float* CB = (const float*)d_in[1];   // [8192, 256]
    float* out = (float*)d_out;
    char* ws = (char*)d_ws;

    const size_t offZb   = 0;                                    // 9,043,968
    const size_t offCb   = offZb + (size_t)M_ROWS * D_DIM * 2;   // +4,194,304
    const size_t offCand = offCb + (size_t)K_CODES * D_DIM * 2;  // +9,043,968
    const size_t offAsum = offCand + (size_t)M_ROWS * 128 * 4;
    const size_t offBsum = offAsum + (size_t)M_ROWS * 4;
    const size_t offLoss = offBsum + (size_t)K_CODES * 4;
    const size_t need    = offLoss + 64;

    if (ws_size >= need) {
        ushort_t* Zb = (ushort_t*)(ws + offZb);
        ushort_t* Cb = (ushort_t*)(ws + offCb);
        unsigned* blockcand = (unsigned*)(ws + offCand);
        float* asum = (float*)(ws + offAsum);
        float* bsum = (float*)(ws + offBsum);
        float* loss_acc = (float*)(ws + offLoss);
        unsigned* ticket = (unsigned*)(ws + offLoss + 16);

        hipLaunchKernelGGL(prep_kernel, dim3(M_ROWS / 32 + K_CODES / 32), dim3(256),
                           0, stream, Z, CB, Zb, Cb, asum, bsum, loss_acc, ticket);
        hipLaunchKernelGGL(phase1_kernel, dim3((M_ROWS / 128) * (K_CODES / 128)),
                           dim3(256), 0, stream, Zb, Cb, bsum, blockcand);
        hipLaunchKernelGGL(phase2_kernel, dim3(M_ROWS / 4), dim3(256), 0, stream,
                           Z, CB, asum, bsum, blockcand, out, loss_acc, ticket);
    } else {
        float* asum = (float*)ws;
        float* bsum = (float*)(ws + (size_t)M_ROWS * 4);
        unsigned long long* packed =
            (unsigned long long*)(ws + (size_t)M_ROWS * 4 + (size_t)K_CODES * 4);
        float* loss_acc =
            (float*)(ws + (size_t)M_ROWS * 4 + (size_t)K_CODES * 4 + (size_t)M_ROWS * 8);

        hipLaunchKernelGGL(init_kernel, dim3((M_ROWS + 255) / 256), dim3(256), 0, stream,
                           packed, loss_acc);
        hipLaunchKernelGGL(rowsq_kernel, dim3((M_ROWS + 255) / 256), dim3(256), 0, stream,
                           Z, asum, M_ROWS);
        hipLaunchKernelGGL(rowsq_kernel, dim3((K_CODES + 255) / 256), dim3(256), 0, stream,
                           CB, bsum, K_CODES);
        hipLaunchKernelGGL(gemm_argmin_kernel, dim3((M_ROWS / BM) * (K_CODES / BN)),
                           dim3(256), 0, stream, Z, CB, asum, bsum, packed);
        hipLaunchKernelGGL(finalize_kernel, dim3(512), dim3(256), 0, stream,
                           Z, CB, packed, out, loss_acc);
        hipLaunchKernelGGL(write_losses, dim3(1), dim3(1), 0, stream, loss_acc, out);
    }
}

// Round 11
// 163.834 us; speedup vs baseline: 1.5265x; 1.5265x over previous
//
#include <hip/hip_runtime.h>
#include <hip/hip_bf16.h>

#define M_ROWS 17664   // B*T = 64*276
#define K_CODES 8192
#define D_DIM 256
#define N_ELEM 4521984 // M_ROWS * 256

typedef unsigned short ushort_t;
typedef __attribute__((ext_vector_type(8))) short short8v;  // 8 bf16 (4 VGPRs)
typedef __attribute__((ext_vector_type(4))) float f32x4;

__device__ __forceinline__ unsigned long long umin64(unsigned long long a, unsigned long long b) { return a < b ? a : b; }

__device__ __forceinline__ unsigned long long shflxor64(unsigned long long v, int m) {
    unsigned lo = (unsigned)v, hi = (unsigned)(v >> 32);
    lo = __shfl_xor(lo, m);
    hi = __shfl_xor(hi, m);
    return ((unsigned long long)hi << 32) | lo;
}

__device__ __forceinline__ void gload16(const void* g, void* l) {
    __builtin_amdgcn_global_load_lds((const __attribute__((address_space(1))) void*)g,
                                     (__attribute__((address_space(3))) void*)l, 16, 0, 0);
}

// ---------------------------------------------------------------------------
// Fused prep (ONE launch for both inputs): coalesced read of 32 rows -> bf16
// copy + EXACT numpy pairwise sum-of-squares (verified chain). LDS stride 257.
// ---------------------------------------------------------------------------
__global__ __launch_bounds__(256) void prep_kernel(
    const float* __restrict__ Z, const float* __restrict__ CB,
    ushort_t* __restrict__ Zb, ushort_t* __restrict__ Cb,
    float* __restrict__ asum, float* __restrict__ bsum,
    float* __restrict__ loss_acc) {
    __shared__ float S[32][257];
    const int t = threadIdx.x;
    const int bid = blockIdx.x;
    const float* X; ushort_t* Xb; float* sums; int r0;
    if (bid < M_ROWS / 32) { X = Z; Xb = Zb; sums = asum; r0 = bid * 32; }
    else { X = CB; Xb = Cb; sums = bsum; r0 = (bid - M_ROWS / 32) * 32; }
    if (bid == 0 && t == 0) loss_acc[0] = 0.0f;
#pragma unroll
    for (int it = 0; it < 8; ++it) {
        int idx4 = t + it * 256;
        int row = idx4 >> 6;
        int c4 = (idx4 & 63) * 4;
        const float4 v = *(const float4*)(X + (size_t)(r0 + row) * D_DIM + c4);
        float vv[4] = {v.x, v.y, v.z, v.w};
        ushort_t h[4];
#pragma unroll
        for (int j = 0; j < 4; ++j) {
            __hip_bfloat16 b = __float2bfloat16(vv[j]);
            h[j] = *reinterpret_cast<ushort_t*>(&b);
        }
        *(ushort4*)(Xb + (size_t)(r0 + row) * D_DIM + c4) =
            make_ushort4(h[0], h[1], h[2], h[3]);
        S[row][c4 + 0] = v.x; S[row][c4 + 1] = v.y;
        S[row][c4 + 2] = v.z; S[row][c4 + 3] = v.w;
    }
    __syncthreads();
    if (t < 32) {
        float half_sum[2];
#pragma unroll
        for (int h = 0; h < 2; ++h) {
            const float* q = &S[t][h * 128];
            float acc[8];
#pragma unroll
            for (int j = 0; j < 8; ++j) acc[j] = __fmul_rn(q[j], q[j]);
            for (int i = 8; i < 128; i += 8) {
#pragma unroll
                for (int j = 0; j < 8; ++j)
                    acc[j] = __fadd_rn(acc[j], __fmul_rn(q[i + j], q[i + j]));
            }
            float s01 = __fadd_rn(acc[0], acc[1]);
            float s23 = __fadd_rn(acc[2], acc[3]);
            float s45 = __fadd_rn(acc[4], acc[5]);
            float s67 = __fadd_rn(acc[6], acc[7]);
            half_sum[h] = __fadd_rn(__fadd_rn(s01, s23), __fadd_rn(s45, s67));
        }
        sums[r0 + t] = __fadd_rn(half_sum[0], half_sum[1]);
    }
}

// ---------------------------------------------------------------------------
// Phase 1 (R10, kept): bf16 MFMA GEMM (Keff=256), 128x128 tile, 4 waves,
// BK=64, SINGLE-buffer (32KB LDS -> 4 blocks/CU) with mid-chunk reissue:
// per chunk: vmcnt(0)+barrier -> ds_read ks0 -> MFMA ks0 -> ds_read ks1 ->
// lgkmcnt(0)+sched_barrier+barrier (all buffer reads done) -> reissue buffer
// for chunk c+1 -> MFMA ks1 (covers load latency; 4 blocks/CU cross-hide).
// BK=64 geometry = R5/R6's measured-ZERO-conflict swizzle (128-B rows,
// slot^(row&7)) on BOTH the pre-swizzled global source (linear gload_lds
// dest, rule #21) and the ds_read slot. MFMA K-order ascending -> acc
// bit-identical to R7/R9.
// Output: blockcand[M][64 bn][2] u32 (d_rel embed, 13-bit col in mantissa).
// ---------------------------------------------------------------------------
__global__ __launch_bounds__(256, 4) void phase1_kernel(
    const ushort_t* __restrict__ Zb,   // [M][256] bf16 bits
    const ushort_t* __restrict__ Cb,   // [K][256] bf16 bits
    const float* __restrict__ bsum,
    unsigned* __restrict__ blockcand) {
    __shared__ ushort_t As[8192];      // z : 128 rows x 64 K-shorts = 16KB
    __shared__ ushort_t Bs[8192];      // cb: 16KB

    const int t = threadIdx.x;
    const int wid = t >> 6, lane = t & 63;
    const int wm = wid >> 1, wn = wid & 1;

    // bijective XCD-grouped mapping: 8832 = 8 xcd * 8 bnsub * 138 bm
    const int bid = blockIdx.x;
    const int bn = ((bid & 7) << 3) + ((bid >> 3) & 7);
    const int bm = bid >> 6;
    const int m0 = bm * 128, n0 = bn * 128;

    f32x4 acc[4][4];
#pragma unroll
    for (int i = 0; i < 4; ++i)
#pragma unroll
        for (int jj = 0; jj < 4; ++jj) acc[i][jj] = (f32x4){0.f, 0.f, 0.f, 0.f};

    // staging geometry (pre-swizzled source slot; linear gload_lds dest).
    const int srow8 = t >> 3;                 // 0..31
    const int sslot = t & 7;
    const int srcq = (sslot ^ (srow8 & 7)) * 8;          // shorts
    const ushort_t* zsrc = Zb + (size_t)(m0 + srow8) * 256 + srcq;
    const ushort_t* csrc = Cb + (size_t)(n0 + srow8) * 256 + srcq;
    const int dst0 = srow8 * 64 + sslot * 8;             // shorts; + i*2048

    // fragment read geometry (R5/R6 proven: phys = (ks*4+q) ^ (fr&7))
    const int fr = lane & 15, q = lane >> 4;
    const int ph0 = (q ^ (fr & 7)) * 8;                  // ks=0, shorts
    const int ph1 = ((4 + q) ^ (fr & 7)) * 8;            // ks=1, shorts

    // ---- prologue: stage chunk 0 ----
#pragma unroll
    for (int i = 0; i < 4; ++i) {
        gload16(zsrc + (size_t)i * 8192, &As[dst0 + i * 2048]);
        gload16(csrc + (size_t)i * 8192, &Bs[dst0 + i * 2048]);
    }

    // ---- main loop: 4 chunks of K=64 ----
#pragma unroll
    for (int c = 0; c < 4; ++c) {
        asm volatile("s_waitcnt vmcnt(0)" ::: "memory");
        __builtin_amdgcn_s_barrier();            // chunk c staged for all waves
        asm volatile("" ::: "memory");

        short8v a0[4], b0[4];
#pragma unroll
        for (int mi = 0; mi < 4; ++mi)
            a0[mi] = *(const short8v*)(&Bs[(wn * 64 + mi * 16 + fr) * 64 + ph0]);
#pragma unroll
        for (int nj = 0; nj < 4; ++nj)
            b0[nj] = *(const short8v*)(&As[(wm * 64 + nj * 16 + fr) * 64 + ph0]);
        __builtin_amdgcn_s_setprio(1);
#pragma unroll
        for (int mi = 0; mi < 4; ++mi)
#pragma unroll
            for (int nj = 0; nj < 4; ++nj)
                acc[mi][nj] = __builtin_amdgcn_mfma_f32_16x16x32_bf16(
                    a0[mi], b0[nj], acc[mi][nj], 0, 0, 0);
        __builtin_amdgcn_s_setprio(0);

        short8v a1[4], b1[4];
#pragma unroll
        for (int mi = 0; mi < 4; ++mi)
            a1[mi] = *(const short8v*)(&Bs[(wn * 64 + mi * 16 + fr) * 64 + ph1]);
#pragma unroll
        for (int nj = 0; nj < 4; ++nj)
            b1[nj] = *(const short8v*)(&As[(wm * 64 + nj * 16 + fr) * 64 + ph1]);
        asm volatile("s_waitcnt lgkmcnt(0)" ::: "memory");
        __builtin_amdgcn_sched_barrier(0);
        __builtin_amdgcn_s_barrier();            // all waves done reading buffer
        asm volatile("" ::: "memory");

        if (c < 3) {                             // reissue buffer for chunk c+1
            const int kc = (c + 1) * 64;         // shorts
#pragma unroll
            for (int i = 0; i < 4; ++i) {
                gload16(zsrc + (size_t)i * 8192 + kc, &As[dst0 + i * 2048]);
                gload16(csrc + (size_t)i * 8192 + kc, &Bs[dst0 + i * 2048]);
            }
        }

        __builtin_amdgcn_s_setprio(1);
#pragma unroll
        for (int mi = 0; mi < 4; ++mi)
#pragma unroll
            for (int nj = 0; nj < 4; ++nj)
                acc[mi][nj] = __builtin_amdgcn_mfma_f32_16x16x32_bf16(
                    a1[mi], b1[nj], acc[mi][nj], 0, 0, 0);
        __builtin_amdgcn_s_setprio(0);
    }

    // ---- epilogue: per z-row top-2 over this wave's 64 cb-cols ----
    unsigned* cand = (unsigned*)&As[0];          // [128][9 stride] u32
    const int colb = n0 + wn * 64 + q * 4;
    float bc16[16];
#pragma unroll
    for (int mi = 0; mi < 4; ++mi)
#pragma unroll
        for (int r = 0; r < 4; ++r)
            bc16[mi * 4 + r] = bsum[colb + mi * 16 + r];

    const float INF = __uint_as_float(0x7f800000u);
#pragma unroll
    for (int nj = 0; nj < 4; ++nj) {
        float m1 = INF, m2 = INF;
#pragma unroll
        for (int mi = 0; mi < 4; ++mi)
#pragma unroll
            for (int r = 0; r < 4; ++r) {
                float dm = __builtin_fmaf(-2.0f, acc[mi][nj][r], bc16[mi * 4 + r]);
                unsigned e = (__float_as_uint(dm) & 0xFFFFE000u) |
                             (unsigned)(colb + mi * 16 + r);
                float fe = __uint_as_float(e);
                m2 = __builtin_amdgcn_fmed3f(m1, m2, fe);
                m1 = fminf(m1, fe);
            }
#pragma unroll
        for (int s = 16; s <= 32; s <<= 1) {
            float o1 = __shfl_xor(m1, s);
            float o2 = __shfl_xor(m2, s);
            float nm2 = fminf(fmaxf(m1, o1), fminf(m2, o2));
            m1 = fminf(m1, o1);
            m2 = nm2;
        }
        if (q == 0) {
            int zr = wm * 64 + nj * 16 + fr;     // 0..127 local row
            cand[zr * 9 + wn * 2 + 0] = __float_as_uint(m1);
            cand[zr * 9 + wn * 2 + 1] = __float_as_uint(m2);
        }
    }
    __syncthreads();
    if (t < 128) {
        float b1 = INF, b2 = INF;
#pragma unroll
        for (int j = 0; j < 4; ++j) {
            float f = __uint_as_float(cand[t * 9 + j]);
            b2 = __builtin_amdgcn_fmed3f(b1, b2, f);
            b1 = fminf(b1, f);
        }
        *(uint2*)(blockcand + (size_t)(m0 + t) * 128 + bn * 2) =
            make_uint2(__float_as_uint(b1), __float_as_uint(b2));
    }
}

// ---------------------------------------------------------------------------
// Phase 2 + finalize (R9 form -- NO device fences/ticket; that cost 110 µs):
// per row (one wave), scan 128 u32 candidates, threshold at dmin_rel + 5e-4,
// exact fp32 np-structured distance per survivor, index tiebreak, then
// z_q_st / min_idx / loss exactly as the verified path.
// ---------------------------------------------------------------------------
__global__ __launch_bounds__(256) void phase2_kernel(
    const float* __restrict__ Z, const float* __restrict__ CB,
    const float* __restrict__ asum, const float* __restrict__ bsum,
    const unsigned* __restrict__ blockcand,
    float* __restrict__ out, float* __restrict__ loss_acc) {
    float* out_zq = out + 2;
    float* out_idx = out + 2 + (size_t)N_ELEM;
    const int lane = threadIdx.x & 63;
    const int w = threadIdx.x >> 6;
    const int row = blockIdx.x * 4 + w;
    float lsum = 0.0f;

    if (row < M_ROWS) {
        const uint2 E = *(const uint2*)(blockcand + (size_t)row * 128 + lane * 2);
        float f0 = __uint_as_float(E.x), f1 = __uint_as_float(E.y);
        float mn = fminf(f0, f1);
#pragma unroll
        for (int s = 1; s < 64; s <<= 1) mn = fminf(mn, __shfl_xor(mn, s));
        const float thr = mn + 5.0e-4f;
        unsigned long long k0m = __ballot(f0 <= thr);
        unsigned long long k1m = __ballot(f1 <= thr);

        const float4 zv = *(const float4*)(Z + (size_t)row * D_DIM + lane * 4);
        float ar = asum[row];
        unsigned long long best = 0xFFFFFFFFFFFFFFFFull;

        while (k0m | k1m) {
            unsigned e;
            if (k0m) { int b = __ffsll(k0m) - 1; k0m &= k0m - 1; e = __shfl(E.x, b); }
            else     { int b = __ffsll(k1m) - 1; k1m &= k1m - 1; e = __shfl(E.y, b); }
            unsigned col = e & 8191u;
            const float4 cv = *(const float4*)(CB + (size_t)col * D_DIM + lane * 4);
            float s = __fmul_rn(zv.x, cv.x);
            s = __builtin_fmaf(zv.y, cv.y, s);
            s = __builtin_fmaf(zv.z, cv.z, s);
            s = __builtin_fmaf(zv.w, cv.w, s);
#pragma unroll
            for (int m = 1; m < 64; m <<= 1) s += __shfl_xor(s, m);
            float d = __fsub_rn(__fadd_rn(ar, bsum[col]), __fmul_rn(2.0f, s));
            unsigned long long p = ((unsigned long long)__float_as_uint(d) << 32) | col;
            best = umin64(best, p);
        }

        unsigned wincol = (unsigned)best;
        if (lane == 0) out_idx[row] = (float)wincol;
        const float4 cv = *(const float4*)(CB + (size_t)wincol * D_DIM + lane * 4);
        float d0 = __fsub_rn(cv.x, zv.x);
        float d1 = __fsub_rn(cv.y, zv.y);
        float d2 = __fsub_rn(cv.z, zv.z);
        float d3 = __fsub_rn(cv.w, zv.w);
        float2 o0 = make_float2(__fadd_rn(zv.x, d0), __fadd_rn(zv.y, d1));
        float2 o1 = make_float2(__fadd_rn(zv.z, d2), __fadd_rn(zv.w, d3));
        *(float2*)(out_zq + (size_t)row * D_DIM + lane * 4) = o0;
        *(float2*)(out_zq + (size_t)row * D_DIM + lane * 4 + 2) = o1;
        lsum = d0 * d0 + d1 * d1 + d2 * d2 + d3 * d3;
    }
#pragma unroll
    for (int m = 1; m < 64; m <<= 1) lsum += __shfl_xor(lsum, m);
    __shared__ float red[4];
    if (lane == 0) red[w] = lsum;
    __syncthreads();
    if (threadIdx.x == 0) {
        float s = ((red[0] + red[1]) + (red[2] + red[3]));
        atomicAdd(loss_acc, s);
    }
}

__global__ void write_losses(const float* __restrict__ loss_acc,
                             float* __restrict__ out) {
    float l = __fdiv_rn(loss_acc[0], (float)N_ELEM);
    out[0] = l;
    out[1] = l;
}

// ======================= fallback path (fp32 VALU, verified) ================
#define BM 128
#define BN 128
#define BK 32
#define LDT 132

__global__ void rowsq_kernel(const float* __restrict__ X,
                             float* __restrict__ out, int rows) {
    int r = blockIdx.x * blockDim.x + threadIdx.x;
    if (r >= rows) return;
    const float* p = X + (size_t)r * D_DIM;
    float half_sum[2];
#pragma unroll
    for (int h = 0; h < 2; ++h) {
        const float* q = p + h * 128;
        float acc[8];
#pragma unroll
        for (int j = 0; j < 8; ++j) acc[j] = __fmul_rn(q[j], q[j]);
        for (int i = 8; i < 128; i += 8) {
#pragma unroll
            for (int j = 0; j < 8; ++j)
                acc[j] = __fadd_rn(acc[j], __fmul_rn(q[i + j], q[i + j]));
        }
        float s01 = __fadd_rn(acc[0], acc[1]);
        float s23 = __fadd_rn(acc[2], acc[3]);
        float s45 = __fadd_rn(acc[4], acc[5]);
        float s67 = __fadd_rn(acc[6], acc[7]);
        half_sum[h] = __fadd_rn(__fadd_rn(s01, s23), __fadd_rn(s45, s67));
    }
    out[r] = __fadd_rn(half_sum[0], half_sum[1]);
}

__global__ void init_kernel(unsigned long long* __restrict__ packed,
                            float* __restrict__ loss_acc) {
    int i = blockIdx.x * blockDim.x + threadIdx.x;
    if (i < M_ROWS) packed[i] = 0xFFFFFFFFFFFFFFFFull;
    if (i == 0) loss_acc[0] = 0.0f;
}

__global__ __launch_bounds__(256) void gemm_argmin_kernel(
    const float* __restrict__ Z, const float* __restrict__ CB,
    const float* __restrict__ asum, const float* __restrict__ bsum,
    unsigned long long* __restrict__ packed) {
    __shared__ float As[BK][LDT];
    __shared__ float Bs[BK][LDT];
    const int bid = blockIdx.x;
    const int bm = bid >> 6, bn = bid & 63;
    const int m0 = bm * BM, n0 = bn * BN;
    const int t = threadIdx.x;
    const int ty = t >> 4, tx = t & 15;
    float acc[8][8];
#pragma unroll
    for (int i = 0; i < 8; ++i)
#pragma unroll
        for (int j = 0; j < 8; ++j) acc[i][j] = 0.0f;
    for (int k0 = 0; k0 < D_DIM; k0 += BK) {
#pragma unroll
        for (int i = 0; i < 4; ++i) {
            int idx = t + i * 256;
            int row = idx >> 3, kq = idx & 7;
            const float4 av = *(const float4*)(Z + (size_t)(m0 + row) * D_DIM + k0 + kq * 4);
            As[kq * 4 + 0][row] = av.x; As[kq * 4 + 1][row] = av.y;
            As[kq * 4 + 2][row] = av.z; As[kq * 4 + 3][row] = av.w;
            const float4 bv = *(const float4*)(CB + (size_t)(n0 + row) * D_DIM + k0 + kq * 4);
            Bs[kq * 4 + 0][row] = bv.x; Bs[kq * 4 + 1][row] = bv.y;
            Bs[kq * 4 + 2][row] = bv.z; Bs[kq * 4 + 3][row] = bv.w;
        }
        __syncthreads();
#pragma unroll
        for (int k = 0; k < BK; ++k) {
            float af[8], bf[8];
            *(float4*)(af)     = *(const float4*)(&As[k][ty * 4]);
            *(float4*)(af + 4) = *(const float4*)(&As[k][64 + ty * 4]);
            *(float4*)(bf)     = *(const float4*)(&Bs[k][tx * 4]);
            *(float4*)(bf + 4) = *(const float4*)(&Bs[k][64 + tx * 4]);
#pragma unroll
            for (int i = 0; i < 8; ++i)
#pragma unroll
                for (int j = 0; j < 8; ++j)
                    acc[i][j] = __builtin_fmaf(af[i], bf[j], acc[i][j]);
        }
        __syncthreads();
    }
    float ar[8], bc[8];
    int rowIdx[8], colIdx[8];
#pragma unroll
    for (int i = 0; i < 8; ++i) {
        rowIdx[i] = (i < 4) ? (4 * ty + i) : (64 + 4 * ty + (i - 4));
        ar[i] = asum[m0 + rowIdx[i]];
    }
#pragma unroll
    for (int j = 0; j < 8; ++j) {
        colIdx[j] = (j < 4) ? (4 * tx + j) : (64 + 4 * tx + (j - 4));
        bc[j] = bsum[n0 + colIdx[j]];
    }
#pragma unroll
    for (int i = 0; i < 8; ++i) {
        unsigned long long best = 0xFFFFFFFFFFFFFFFFull;
#pragma unroll
        for (int j = 0; j < 8; ++j) {
            float ts = __fadd_rn(ar[i], bc[j]);
            float d = __fsub_rn(ts, __fmul_rn(2.0f, acc[i][j]));
            unsigned long long p = ((unsigned long long)__float_as_uint(d) << 32) |
                                   (unsigned)(n0 + colIdx[j]);
            best = (p < best) ? p : best;
        }
#pragma unroll
        for (int m = 1; m <= 8; m <<= 1) {
            unsigned long long o = shflxor64(best, m);
            best = (o < best) ? o : best;
        }
        if (tx == 0) atomicMin(&packed[m0 + rowIdx[i]], best);
    }
}

__global__ __launch_bounds__(256) void finalize_kernel(
    const float* __restrict__ Z, const float* __restrict__ CB,
    const unsigned long long* __restrict__ packed,
    float* __restrict__ out, float* __restrict__ loss_acc) {
    float* out_zq = out + 2;
    float* out_idx = out + 2 + (size_t)N_ELEM;
    const int lane = threadIdx.x & 63;
    const int wid = (blockIdx.x * blockDim.x + threadIdx.x) >> 6;
    const int nw = (gridDim.x * blockDim.x) >> 6;
    float lsum = 0.0f;
    for (int row = wid; row < M_ROWS; row += nw) {
        unsigned long long pk = packed[row];
        unsigned idx = (unsigned)(pk & 0xFFFFFFFFull);
        if (lane == 0) out_idx[row] = (float)idx;
        const float4 zv = *(const float4*)(Z + (size_t)row * D_DIM + lane * 4);
        const float4 cv = *(const float4*)(CB + (size_t)idx * D_DIM + lane * 4);
        float d0 = __fsub_rn(cv.x, zv.x);
        float d1 = __fsub_rn(cv.y, zv.y);
        float d2 = __fsub_rn(cv.z, zv.z);
        float d3 = __fsub_rn(cv.w, zv.w);
        float2 o0 = make_float2(__fadd_rn(zv.x, d0), __fadd_rn(zv.y, d1));
        float2 o1 = make_float2(__fadd_rn(zv.z, d2), __fadd_rn(zv.w, d3));
        *(float2*)(out_zq + (size_t)row * D_DIM + lane * 4) = o0;
        *(float2*)(out_zq + (size_t)row * D_DIM + lane * 4 + 2) = o1;
        lsum += d0 * d0 + d1 * d1 + d2 * d2 + d3 * d3;
    }
#pragma unroll
    for (int m = 1; m < 64; m <<= 1) lsum += __shfl_xor(lsum, m);
    __shared__ float red[4];
    if (lane == 0) red[threadIdx.x >> 6] = lsum;
    __syncthreads();
    if (threadIdx.x == 0) {
        float s = ((red[0] + red[1]) + (red[2] + red[3]));
        atomicAdd(loss_acc, s);
    }
}

// ===========================================================================
extern "C" void kernel_launch(void* const* d_in, const int* in_sizes, int n_in,
                              void* d_out, int out_size, void* d_ws, size_t ws_size,
                              hipStream_t stream) {
    const float* Z = (const float*)d_in[0];    // [17664, 256]
    const float* CB = (const float*)d_in[1];   // [8192, 256]
    float* out = (float*)d_out;
    char* ws = (char*)d_ws;

    const size_t offZb   = 0;                                    // 9,043,968
    const size_t offCb   = offZb + (size_t)M_ROWS * D_DIM * 2;   // +4,194,304
    const size_t offCand = offCb + (size_t)K_CODES * D_DIM * 2;  // +9,043,968
    const size_t offAsum = offCand + (size_t)M_ROWS * 128 * 4;
    const size_t offBsum = offAsum + (size_t)M_ROWS * 4;
    const size_t offLoss = offBsum + (size_t)K_CODES * 4;
    const size_t need    = offLoss + 64;

    if (ws_size >= need) {
        ushort_t* Zb = (ushort_t*)(ws + offZb);
        ushort_t* Cb = (ushort_t*)(ws + offCb);
        unsigned* blockcand = (unsigned*)(ws + offCand);
        float* asum = (float*)(ws + offAsum);
        float* bsum = (float*)(ws + offBsum);
        float* loss_acc = (float*)(ws + offLoss);

        hipLaunchKernelGGL(prep_kernel, dim3(M_ROWS / 32 + K_CODES / 32), dim3(256),
                           0, stream, Z, CB, Zb, Cb, asum, bsum, loss_acc);
        hipLaunchKernelGGL(phase1_kernel, dim3((M_ROWS / 128) * (K_CODES / 128)),
                           dim3(256), 0, stream, Zb, Cb, bsum, blockcand);
        hipLaunchKernelGGL(phase2_kernel, dim3(M_ROWS / 4), dim3(256), 0, stream,
                           Z, CB, asum, bsum, blockcand, out, loss_acc);
        hipLaunchKernelGGL(write_losses, dim3(1), dim3(1), 0, stream, loss_acc, out);
    } else {
        float* asum = (float*)ws;
        float* bsum = (float*)(ws + (size_t)M_ROWS * 4);
        unsigned long long* packed =
            (unsigned long long*)(ws + (size_t)M_ROWS * 4 + (size_t)K_CODES * 4);
        float* loss_acc =
            (float*)(ws + (size_t)M_ROWS * 4 + (size_t)K_CODES * 4 + (size_t)M_ROWS * 8);

        hipLaunchKernelGGL(init_kernel, dim3((M_ROWS + 255) / 256), dim3(256), 0, stream,
                           packed, loss_acc);
        hipLaunchKernelGGL(rowsq_kernel, dim3((M_ROWS + 255) / 256), dim3(256), 0, stream,
                           Z, asum, M_ROWS);
        hipLaunchKernelGGL(rowsq_kernel, dim3((K_CODES + 255) / 256), dim3(256), 0, stream,
                           CB, bsum, K_CODES);
        hipLaunchKernelGGL(gemm_argmin_kernel, dim3((M_ROWS / BM) * (K_CODES / BN)),
                           dim3(256), 0, stream, Z, CB, asum, bsum, packed);
        hipLaunchKernelGGL(finalize_kernel, dim3(512), dim3(256), 0, stream,
                           Z, CB, packed, out, loss_acc);
        hipLaunchKernelGGL(write_losses, dim3(1), dim3(1), 0, stream, loss_acc, out);
    }
}

// Round 12
// 129.968 us; speedup vs baseline: 1.9242x; 1.2606x over previous
//
#include <hip/hip_runtime.h>
#include <hip/hip_bf16.h>

#define M_ROWS 17664   // B*T = 64*276
#define K_CODES 8192
#define D_DIM 256
#define N_ELEM 4521984 // M_ROWS * 256

typedef unsigned short ushort_t;
typedef __attribute__((ext_vector_type(8))) short short8v;  // 8 bf16 (4 VGPRs)
typedef __attribute__((ext_vector_type(4))) float f32x4;

__device__ __forceinline__ unsigned long long umin64(unsigned long long a, unsigned long long b) { return a < b ? a : b; }

__device__ __forceinline__ unsigned long long shflxor64(unsigned long long v, int m) {
    unsigned lo = (unsigned)v, hi = (unsigned)(v >> 32);
    lo = __shfl_xor(lo, m);
    hi = __shfl_xor(hi, m);
    return ((unsigned long long)hi << 32) | lo;
}

__device__ __forceinline__ void gload16(const void* g, void* l) {
    __builtin_amdgcn_global_load_lds((const __attribute__((address_space(1))) void*)g,
                                     (__attribute__((address_space(3))) void*)l, 16, 0, 0);
}

// ---------------------------------------------------------------------------
// Fused prep (ONE launch for both inputs): coalesced read of 32 rows -> bf16
// copy + EXACT numpy pairwise sum-of-squares (verified chain). LDS stride 257.
// ---------------------------------------------------------------------------
__global__ __launch_bounds__(256) void prep_kernel(
    const float* __restrict__ Z, const float* __restrict__ CB,
    ushort_t* __restrict__ Zb, ushort_t* __restrict__ Cb,
    float* __restrict__ asum, float* __restrict__ bsum,
    float* __restrict__ loss_acc) {
    __shared__ float S[32][257];
    const int t = threadIdx.x;
    const int bid = blockIdx.x;
    const float* X; ushort_t* Xb; float* sums; int r0;
    if (bid < M_ROWS / 32) { X = Z; Xb = Zb; sums = asum; r0 = bid * 32; }
    else { X = CB; Xb = Cb; sums = bsum; r0 = (bid - M_ROWS / 32) * 32; }
    if (bid == 0 && t == 0) loss_acc[0] = 0.0f;
#pragma unroll
    for (int it = 0; it < 8; ++it) {
        int idx4 = t + it * 256;
        int row = idx4 >> 6;
        int c4 = (idx4 & 63) * 4;
        const float4 v = *(const float4*)(X + (size_t)(r0 + row) * D_DIM + c4);
        float vv[4] = {v.x, v.y, v.z, v.w};
        ushort_t h[4];
#pragma unroll
        for (int j = 0; j < 4; ++j) {
            __hip_bfloat16 b = __float2bfloat16(vv[j]);
            h[j] = *reinterpret_cast<ushort_t*>(&b);
        }
        *(ushort4*)(Xb + (size_t)(r0 + row) * D_DIM + c4) =
            make_ushort4(h[0], h[1], h[2], h[3]);
        S[row][c4 + 0] = v.x; S[row][c4 + 1] = v.y;
        S[row][c4 + 2] = v.z; S[row][c4 + 3] = v.w;
    }
    __syncthreads();
    if (t < 32) {
        float half_sum[2];
#pragma unroll
        for (int h = 0; h < 2; ++h) {
            const float* q = &S[t][h * 128];
            float acc[8];
#pragma unroll
            for (int j = 0; j < 8; ++j) acc[j] = __fmul_rn(q[j], q[j]);
            for (int i = 8; i < 128; i += 8) {
#pragma unroll
                for (int j = 0; j < 8; ++j)
                    acc[j] = __fadd_rn(acc[j], __fmul_rn(q[i + j], q[i + j]));
            }
            float s01 = __fadd_rn(acc[0], acc[1]);
            float s23 = __fadd_rn(acc[2], acc[3]);
            float s45 = __fadd_rn(acc[4], acc[5]);
            float s67 = __fadd_rn(acc[6], acc[7]);
            half_sum[h] = __fadd_rn(__fadd_rn(s01, s23), __fadd_rn(s45, s67));
        }
        sums[r0 + t] = __fadd_rn(half_sum[0], half_sum[1]);
    }
}

// ---------------------------------------------------------------------------
// Phase 1 (R11, UNCHANGED -- at m97-structure ceiling: 88us, MfmaUtil 37%,
// bank conflicts 0): bf16 MFMA GEMM (Keff=256), 128x128 tile, 4 waves,
// BK=64, single-buffer 32KB LDS, mid-chunk reissue, counted waits.
// ---------------------------------------------------------------------------
__global__ __launch_bounds__(256, 4) void phase1_kernel(
    const ushort_t* __restrict__ Zb,   // [M][256] bf16 bits
    const ushort_t* __restrict__ Cb,   // [K][256] bf16 bits
    const float* __restrict__ bsum,
    unsigned* __restrict__ blockcand) {
    __shared__ ushort_t As[8192];      // z : 128 rows x 64 K-shorts = 16KB
    __shared__ ushort_t Bs[8192];      // cb: 16KB

    const int t = threadIdx.x;
    const int wid = t >> 6, lane = t & 63;
    const int wm = wid >> 1, wn = wid & 1;

    const int bid = blockIdx.x;
    const int bn = ((bid & 7) << 3) + ((bid >> 3) & 7);
    const int bm = bid >> 6;
    const int m0 = bm * 128, n0 = bn * 128;

    f32x4 acc[4][4];
#pragma unroll
    for (int i = 0; i < 4; ++i)
#pragma unroll
        for (int jj = 0; jj < 4; ++jj) acc[i][jj] = (f32x4){0.f, 0.f, 0.f, 0.f};

    const int srow8 = t >> 3;                 // 0..31
    const int sslot = t & 7;
    const int srcq = (sslot ^ (srow8 & 7)) * 8;          // shorts
    const ushort_t* zsrc = Zb + (size_t)(m0 + srow8) * 256 + srcq;
    const ushort_t* csrc = Cb + (size_t)(n0 + srow8) * 256 + srcq;
    const int dst0 = srow8 * 64 + sslot * 8;             // shorts; + i*2048

    const int fr = lane & 15, q = lane >> 4;
    const int ph0 = (q ^ (fr & 7)) * 8;                  // ks=0, shorts
    const int ph1 = ((4 + q) ^ (fr & 7)) * 8;            // ks=1, shorts

#pragma unroll
    for (int i = 0; i < 4; ++i) {
        gload16(zsrc + (size_t)i * 8192, &As[dst0 + i * 2048]);
        gload16(csrc + (size_t)i * 8192, &Bs[dst0 + i * 2048]);
    }

#pragma unroll
    for (int c = 0; c < 4; ++c) {
        asm volatile("s_waitcnt vmcnt(0)" ::: "memory");
        __builtin_amdgcn_s_barrier();
        asm volatile("" ::: "memory");

        short8v a0[4], b0[4];
#pragma unroll
        for (int mi = 0; mi < 4; ++mi)
            a0[mi] = *(const short8v*)(&Bs[(wn * 64 + mi * 16 + fr) * 64 + ph0]);
#pragma unroll
        for (int nj = 0; nj < 4; ++nj)
            b0[nj] = *(const short8v*)(&As[(wm * 64 + nj * 16 + fr) * 64 + ph0]);
        __builtin_amdgcn_s_setprio(1);
#pragma unroll
        for (int mi = 0; mi < 4; ++mi)
#pragma unroll
            for (int nj = 0; nj < 4; ++nj)
                acc[mi][nj] = __builtin_amdgcn_mfma_f32_16x16x32_bf16(
                    a0[mi], b0[nj], acc[mi][nj], 0, 0, 0);
        __builtin_amdgcn_s_setprio(0);

        short8v a1[4], b1[4];
#pragma unroll
        for (int mi = 0; mi < 4; ++mi)
            a1[mi] = *(const short8v*)(&Bs[(wn * 64 + mi * 16 + fr) * 64 + ph1]);
#pragma unroll
        for (int nj = 0; nj < 4; ++nj)
            b1[nj] = *(const short8v*)(&As[(wm * 64 + nj * 16 + fr) * 64 + ph1]);
        asm volatile("s_waitcnt lgkmcnt(0)" ::: "memory");
        __builtin_amdgcn_sched_barrier(0);
        __builtin_amdgcn_s_barrier();
        asm volatile("" ::: "memory");

        if (c < 3) {
            const int kc = (c + 1) * 64;         // shorts
#pragma unroll
            for (int i = 0; i < 4; ++i) {
                gload16(zsrc + (size_t)i * 8192 + kc, &As[dst0 + i * 2048]);
                gload16(csrc + (size_t)i * 8192 + kc, &Bs[dst0 + i * 2048]);
            }
        }

        __builtin_amdgcn_s_setprio(1);
#pragma unroll
        for (int mi = 0; mi < 4; ++mi)
#pragma unroll
            for (int nj = 0; nj < 4; ++nj)
                acc[mi][nj] = __builtin_amdgcn_mfma_f32_16x16x32_bf16(
                    a1[mi], b1[nj], acc[mi][nj], 0, 0, 0);
        __builtin_amdgcn_s_setprio(0);
    }

    // ---- epilogue: per z-row top-2 over this wave's 64 cb-cols ----
    unsigned* cand = (unsigned*)&As[0];          // [128][9 stride] u32
    const int colb = n0 + wn * 64 + q * 4;
    float bc16[16];
#pragma unroll
    for (int mi = 0; mi < 4; ++mi)
#pragma unroll
        for (int r = 0; r < 4; ++r)
            bc16[mi * 4 + r] = bsum[colb + mi * 16 + r];

    const float INF = __uint_as_float(0x7f800000u);
#pragma unroll
    for (int nj = 0; nj < 4; ++nj) {
        float m1 = INF, m2 = INF;
#pragma unroll
        for (int mi = 0; mi < 4; ++mi)
#pragma unroll
            for (int r = 0; r < 4; ++r) {
                float dm = __builtin_fmaf(-2.0f, acc[mi][nj][r], bc16[mi * 4 + r]);
                unsigned e = (__float_as_uint(dm) & 0xFFFFE000u) |
                             (unsigned)(colb + mi * 16 + r);
                float fe = __uint_as_float(e);
                m2 = __builtin_amdgcn_fmed3f(m1, m2, fe);
                m1 = fminf(m1, fe);
            }
#pragma unroll
        for (int s = 16; s <= 32; s <<= 1) {
            float o1 = __shfl_xor(m1, s);
            float o2 = __shfl_xor(m2, s);
            float nm2 = fminf(fmaxf(m1, o1), fminf(m2, o2));
            m1 = fminf(m1, o1);
            m2 = nm2;
        }
        if (q == 0) {
            int zr = wm * 64 + nj * 16 + fr;     // 0..127 local row
            cand[zr * 9 + wn * 2 + 0] = __float_as_uint(m1);
            cand[zr * 9 + wn * 2 + 1] = __float_as_uint(m2);
        }
    }
    __syncthreads();
    if (t < 128) {
        float b1 = INF, b2 = INF;
#pragma unroll
        for (int j = 0; j < 4; ++j) {
            float f = __uint_as_float(cand[t * 9 + j]);
            b2 = __builtin_amdgcn_fmed3f(b1, b2, f);
            b1 = fminf(b1, f);
        }
        *(uint2*)(blockcand + (size_t)(m0 + t) * 128 + bn * 2) =
            make_uint2(__float_as_uint(b1), __float_as_uint(b2));
    }
}

// ---------------------------------------------------------------------------
// Phase 2 v2 (latency attack): 1104 blocks x 4 waves; each wave handles 4
// rows (stride 4416) with a 2-deep software pipeline -- next row's blockcand/
// Z/asum loads issue BEFORE the current row's dependent chain, hiding the
// ~900-cyc HBM latency. Winner's CB row is kept in registers from the
// survivor loop (no re-gather). One atomicAdd per block (1104 vs 4416), no
// device fences (R10 lesson). Selection math identical to the verified path.
// ---------------------------------------------------------------------------
__global__ __launch_bounds__(256) void phase2_kernel(
    const float* __restrict__ Z, const float* __restrict__ CB,
    const float* __restrict__ asum, const float* __restrict__ bsum,
    const unsigned* __restrict__ blockcand,
    float* __restrict__ out, float* __restrict__ loss_acc) {
    float* out_zq = out + 2;
    float* out_idx = out + 2 + (size_t)N_ELEM;
    const int lane = threadIdx.x & 63;
    const int w = threadIdx.x >> 6;
    const int gw = blockIdx.x * 4 + w;       // 0..4415
    const int NW = M_ROWS / 4;               // 4416
    float lsum = 0.0f;

    int row = gw;
    uint2 E = *(const uint2*)(blockcand + (size_t)row * 128 + lane * 2);
    float4 zv = *(const float4*)(Z + (size_t)row * D_DIM + lane * 4);
    float ar = asum[row];

#pragma unroll 1
    for (int it = 0; it < 4; ++it) {
        const int nrow = row + NW;
        uint2 En = E; float4 zvn = zv; float arn = ar;
        if (it < 3) {   // prefetch next row (hides under current processing)
            En = *(const uint2*)(blockcand + (size_t)nrow * 128 + lane * 2);
            zvn = *(const float4*)(Z + (size_t)nrow * D_DIM + lane * 4);
            arn = asum[nrow];
        }

        float f0 = __uint_as_float(E.x), f1 = __uint_as_float(E.y);
        float mn = fminf(f0, f1);
#pragma unroll
        for (int s = 1; s < 64; s <<= 1) mn = fminf(mn, __shfl_xor(mn, s));
        const float thr = mn + 5.0e-4f;
        unsigned long long k0m = __ballot(f0 <= thr);
        unsigned long long k1m = __ballot(f1 <= thr);

        unsigned long long best = 0xFFFFFFFFFFFFFFFFull;
        float4 bcv = make_float4(0.f, 0.f, 0.f, 0.f);

        while (k0m | k1m) {
            unsigned e;
            if (k0m) { int b = __ffsll(k0m) - 1; k0m &= k0m - 1; e = __shfl(E.x, b); }
            else     { int b = __ffsll(k1m) - 1; k1m &= k1m - 1; e = __shfl(E.y, b); }
            unsigned col = e & 8191u;
            const float4 cv = *(const float4*)(CB + (size_t)col * D_DIM + lane * 4);
            float s = __fmul_rn(zv.x, cv.x);
            s = __builtin_fmaf(zv.y, cv.y, s);
            s = __builtin_fmaf(zv.z, cv.z, s);
            s = __builtin_fmaf(zv.w, cv.w, s);
#pragma unroll
            for (int m = 1; m < 64; m <<= 1) s += __shfl_xor(s, m);
            float d = __fsub_rn(__fadd_rn(ar, bsum[col]), __fmul_rn(2.0f, s));
            unsigned long long p = ((unsigned long long)__float_as_uint(d) << 32) | col;
            if (p < best) { best = p; bcv = cv; }   // wave-uniform select
        }

        unsigned wincol = (unsigned)best;
        if (lane == 0) out_idx[row] = (float)wincol;
        float d0 = __fsub_rn(bcv.x, zv.x);
        float d1 = __fsub_rn(bcv.y, zv.y);
        float d2 = __fsub_rn(bcv.z, zv.z);
        float d3 = __fsub_rn(bcv.w, zv.w);
        float2 o0 = make_float2(__fadd_rn(zv.x, d0), __fadd_rn(zv.y, d1));
        float2 o1 = make_float2(__fadd_rn(zv.z, d2), __fadd_rn(zv.w, d3));
        *(float2*)(out_zq + (size_t)row * D_DIM + lane * 4) = o0;
        *(float2*)(out_zq + (size_t)row * D_DIM + lane * 4 + 2) = o1;
        lsum += d0 * d0 + d1 * d1 + d2 * d2 + d3 * d3;

        row = nrow; E = En; zv = zvn; ar = arn;
    }

#pragma unroll
    for (int m = 1; m < 64; m <<= 1) lsum += __shfl_xor(lsum, m);
    __shared__ float red[4];
    if (lane == 0) red[w] = lsum;
    __syncthreads();
    if (threadIdx.x == 0) {
        float s = ((red[0] + red[1]) + (red[2] + red[3]));
        atomicAdd(loss_acc, s);
    }
}

__global__ void write_losses(const float* __restrict__ loss_acc,
                             float* __restrict__ out) {
    float l = __fdiv_rn(loss_acc[0], (float)N_ELEM);
    out[0] = l;
    out[1] = l;
}

// ======================= fallback path (fp32 VALU, verified) ================
#define BM 128
#define BN 128
#define BK 32
#define LDT 132

__global__ void rowsq_kernel(const float* __restrict__ X,
                             float* __restrict__ out, int rows) {
    int r = blockIdx.x * blockDim.x + threadIdx.x;
    if (r >= rows) return;
    const float* p = X + (size_t)r * D_DIM;
    float half_sum[2];
#pragma unroll
    for (int h = 0; h < 2; ++h) {
        const float* q = p + h * 128;
        float acc[8];
#pragma unroll
        for (int j = 0; j < 8; ++j) acc[j] = __fmul_rn(q[j], q[j]);
        for (int i = 8; i < 128; i += 8) {
#pragma unroll
            for (int j = 0; j < 8; ++j)
                acc[j] = __fadd_rn(acc[j], __fmul_rn(q[i + j], q[i + j]));
        }
        float s01 = __fadd_rn(acc[0], acc[1]);
        float s23 = __fadd_rn(acc[2], acc[3]);
        float s45 = __fadd_rn(acc[4], acc[5]);
        float s67 = __fadd_rn(acc[6], acc[7]);
        half_sum[h] = __fadd_rn(__fadd_rn(s01, s23), __fadd_rn(s45, s67));
    }
    out[r] = __fadd_rn(half_sum[0], half_sum[1]);
}

__global__ void init_kernel(unsigned long long* __restrict__ packed,
                            float* __restrict__ loss_acc) {
    int i = blockIdx.x * blockDim.x + threadIdx.x;
    if (i < M_ROWS) packed[i] = 0xFFFFFFFFFFFFFFFFull;
    if (i == 0) loss_acc[0] = 0.0f;
}

__global__ __launch_bounds__(256) void gemm_argmin_kernel(
    const float* __restrict__ Z, const float* __restrict__ CB,
    const float* __restrict__ asum, const float* __restrict__ bsum,
    unsigned long long* __restrict__ packed) {
    __shared__ float As[BK][LDT];
    __shared__ float Bs[BK][LDT];
    const int bid = blockIdx.x;
    const int bm = bid >> 6, bn = bid & 63;
    const int m0 = bm * BM, n0 = bn * BN;
    const int t = threadIdx.x;
    const int ty = t >> 4, tx = t & 15;
    float acc[8][8];
#pragma unroll
    for (int i = 0; i < 8; ++i)
#pragma unroll
        for (int j = 0; j < 8; ++j) acc[i][j] = 0.0f;
    for (int k0 = 0; k0 < D_DIM; k0 += BK) {
#pragma unroll
        for (int i = 0; i < 4; ++i) {
            int idx = t + i * 256;
            int row = idx >> 3, kq = idx & 7;
            const float4 av = *(const float4*)(Z + (size_t)(m0 + row) * D_DIM + k0 + kq * 4);
            As[kq * 4 + 0][row] = av.x; As[kq * 4 + 1][row] = av.y;
            As[kq * 4 + 2][row] = av.z; As[kq * 4 + 3][row] = av.w;
            const float4 bv = *(const float4*)(CB + (size_t)(n0 + row) * D_DIM + k0 + kq * 4);
            Bs[kq * 4 + 0][row] = bv.x; Bs[kq * 4 + 1][row] = bv.y;
            Bs[kq * 4 + 2][row] = bv.z; Bs[kq * 4 + 3][row] = bv.w;
        }
        __syncthreads();
#pragma unroll
        for (int k = 0; k < BK; ++k) {
            float af[8], bf[8];
            *(float4*)(af)     = *(const float4*)(&As[k][ty * 4]);
            *(float4*)(af + 4) = *(const float4*)(&As[k][64 + ty * 4]);
            *(float4*)(bf)     = *(const float4*)(&Bs[k][tx * 4]);
            *(float4*)(bf + 4) = *(const float4*)(&Bs[k][64 + tx * 4]);
#pragma unroll
            for (int i = 0; i < 8; ++i)
#pragma unroll
                for (int j = 0; j < 8; ++j)
                    acc[i][j] = __builtin_fmaf(af[i], bf[j], acc[i][j]);
        }
        __syncthreads();
    }
    float ar[8], bc[8];
    int rowIdx[8], colIdx[8];
#pragma unroll
    for (int i = 0; i < 8; ++i) {
        rowIdx[i] = (i < 4) ? (4 * ty + i) : (64 + 4 * ty + (i - 4));
        ar[i] = asum[m0 + rowIdx[i]];
    }
#pragma unroll
    for (int j = 0; j < 8; ++j) {
        colIdx[j] = (j < 4) ? (4 * tx + j) : (64 + 4 * tx + (j - 4));
        bc[j] = bsum[n0 + colIdx[j]];
    }
#pragma unroll
    for (int i = 0; i < 8; ++i) {
        unsigned long long best = 0xFFFFFFFFFFFFFFFFull;
#pragma unroll
        for (int j = 0; j < 8; ++j) {
            float ts = __fadd_rn(ar[i], bc[j]);
            float d = __fsub_rn(ts, __fmul_rn(2.0f, acc[i][j]));
            unsigned long long p = ((unsigned long long)__float_as_uint(d) << 32) |
                                   (unsigned)(n0 + colIdx[j]);
            best = (p < best) ? p : best;
        }
#pragma unroll
        for (int m = 1; m <= 8; m <<= 1) {
            unsigned long long o = shflxor64(best, m);
            best = (o < best) ? o : best;
        }
        if (tx == 0) atomicMin(&packed[m0 + rowIdx[i]], best);
    }
}

__global__ __launch_bounds__(256) void finalize_kernel(
    const float* __restrict__ Z, const float* __restrict__ CB,
    const unsigned long long* __restrict__ packed,
    float* __restrict__ out, float* __restrict__ loss_acc) {
    float* out_zq = out + 2;
    float* out_idx = out + 2 + (size_t)N_ELEM;
    const int lane = threadIdx.x & 63;
    const int wid = (blockIdx.x * blockDim.x + threadIdx.x) >> 6;
    const int nw = (gridDim.x * blockDim.x) >> 6;
    float lsum = 0.0f;
    for (int row = wid; row < M_ROWS; row += nw) {
        unsigned long long pk = packed[row];
        unsigned idx = (unsigned)(pk & 0xFFFFFFFFull);
        if (lane == 0) out_idx[row] = (float)idx;
        const float4 zv = *(const float4*)(Z + (size_t)row * D_DIM + lane * 4);
        const float4 cv = *(const float4*)(CB + (size_t)idx * D_DIM + lane * 4);
        float d0 = __fsub_rn(cv.x, zv.x);
        float d1 = __fsub_rn(cv.y, zv.y);
        float d2 = __fsub_rn(cv.z, zv.z);
        float d3 = __fsub_rn(cv.w, zv.w);
        float2 o0 = make_float2(__fadd_rn(zv.x, d0), __fadd_rn(zv.y, d1));
        float2 o1 = make_float2(__fadd_rn(zv.z, d2), __fadd_rn(zv.w, d3));
        *(float2*)(out_zq + (size_t)row * D_DIM + lane * 4) = o0;
        *(float2*)(out_zq + (size_t)row * D_DIM + lane * 4 + 2) = o1;
        lsum += d0 * d0 + d1 * d1 + d2 * d2 + d3 * d3;
    }
#pragma unroll
    for (int m = 1; m < 64; m <<= 1) lsum += __shfl_xor(lsum, m);
    __shared__ float red[4];
    if (lane == 0) red[threadIdx.x >> 6] = lsum;
    __syncthreads();
    if (threadIdx.x == 0) {
        float s = ((red[0] + red[1]) + (red[2] + red[3]));
        atomicAdd(loss_acc, s);
    }
}

// ===========================================================================
extern "C" void kernel_launch(void* const* d_in, const int* in_sizes, int n_in,
                              void* d_out, int out_size, void* d_ws, size_t ws_size,
                              hipStream_t stream) {
    const float* Z = (const float*)d_in[0];    // [17664, 256]
    const float* CB = (const float*)d_in[1];   // [8192, 256]
    float* out = (float*)d_out;
    char* ws = (char*)d_ws;

    const size_t offZb   = 0;                                    // 9,043,968
    const size_t offCb   = offZb + (size_t)M_ROWS * D_DIM * 2;   // +4,194,304
    const size_t offCand = offCb + (size_t)K_CODES * D_DIM * 2;  // +9,043,968
    const size_t offAsum = offCand + (size_t)M_ROWS * 128 * 4;
    const size_t offBsum = offAsum + (size_t)M_ROWS * 4;
    const size_t offLoss = offBsum + (size_t)K_CODES * 4;
    const size_t need    = offLoss + 64;

    if (ws_size >= need) {
        ushort_t* Zb = (ushort_t*)(ws + offZb);
        ushort_t* Cb = (ushort_t*)(ws + offCb);
        unsigned* blockcand = (unsigned*)(ws + offCand);
        float* asum = (float*)(ws + offAsum);
        float* bsum = (float*)(ws + offBsum);
        float* loss_acc = (float*)(ws + offLoss);

        hipLaunchKernelGGL(prep_kernel, dim3(M_ROWS / 32 + K_CODES / 32), dim3(256),
                           0, stream, Z, CB, Zb, Cb, asum, bsum, loss_acc);
        hipLaunchKernelGGL(phase1_kernel, dim3((M_ROWS / 128) * (K_CODES / 128)),
                           dim3(256), 0, stream, Zb, Cb, bsum, blockcand);
        hipLaunchKernelGGL(phase2_kernel, dim3(M_ROWS / 16), dim3(256), 0, stream,
                           Z, CB, asum, bsum, blockcand, out, loss_acc);
        hipLaunchKernelGGL(write_losses, dim3(1), dim3(1), 0, stream, loss_acc, out);
    } else {
        float* asum = (float*)ws;
        float* bsum = (float*)(ws + (size_t)M_ROWS * 4);
        unsigned long long* packed =
            (unsigned long long*)(ws + (size_t)M_ROWS * 4 + (size_t)K_CODES * 4);
        float* loss_acc =
            (float*)(ws + (size_t)M_ROWS * 4 + (size_t)K_CODES * 4 + (size_t)M_ROWS * 8);

        hipLaunchKernelGGL(init_kernel, dim3((M_ROWS + 255) / 256), dim3(256), 0, stream,
                           packed, loss_acc);
        hipLaunchKernelGGL(rowsq_kernel, dim3((M_ROWS + 255) / 256), dim3(256), 0, stream,
                           Z, asum, M_ROWS);
        hipLaunchKernelGGL(rowsq_kernel, dim3((K_CODES + 255) / 256), dim3(256), 0, stream,
                           CB, bsum, K_CODES);
        hipLaunchKernelGGL(gemm_argmin_kernel, dim3((M_ROWS / BM) * (K_CODES / BN)),
                           dim3(256), 0, stream, Z, CB, asum, bsum, packed);
        hipLaunchKernelGGL(finalize_kernel, dim3(512), dim3(256), 0, stream,
                           Z, CB, packed, out, loss_acc);
        hipLaunchKernelGGL(write_losses, dim3(1), dim3(1), 0, stream, loss_acc, out);
    }
}